// Round 14
// baseline (87.416 us; speedup 1.0000x reference)
//
#include <hip/hip_runtime.h>
#include <hip/hip_bf16.h>

// Problem constants
#define B_    64
#define S_    512
#define L_    256
#define D_    768      // K of GEMM1
#define RED_  400
#define REDP_ 512      // padded N of GEMM1 / K-stride of GEMM23
#define KEFF_ 416      // effective K of GEMM23 (13 k-tiles; h cols 400.. are 0)
#define HID_  100
#define HIDP_ 128      // padded N of GEMM23 / K of aff+triplet
#define TAGS_ 5
#define POL_  4
#define NBI_  512      // aff padded N (4 * 128)
#define NAO_  256      // fused ap|op GEMM N
#define BL_   (B_ * L_)  // 16384

typedef __attribute__((ext_vector_type(8))) short short8;
typedef __attribute__((ext_vector_type(4))) float f32x4;
typedef __attribute__((ext_vector_type(4))) unsigned short u16x4;

#define GLOAD_LDS16(gp, lp) __builtin_amdgcn_global_load_lds( \
    (const __attribute__((address_space(1))) void*)(gp),      \
    (__attribute__((address_space(3))) void*)(lp), 16, 0, 0)

__device__ inline float bf2f(unsigned short u) {
    union { unsigned int i; float f; } c; c.i = ((unsigned)u) << 16; return c.f;
}
__device__ inline unsigned short f2bf(float f) {
    __hip_bfloat16 h = __float2bfloat16(f);
    unsigned short u;
    __builtin_memcpy(&u, &h, 2);
    return u;
}

// ---------------------------------------------------------------------------
// 0) PREP: weight/bias prep only.
// ---------------------------------------------------------------------------
#define SZ0 393216
#define SZ1 131072
#define SZ2 65536
#define SZ3 512
#define SZ4 256
#define PREP_TOT (SZ0 + SZ1 + SZ2 + SZ3 + SZ4)
#define PREP_BLOCKS ((PREP_TOT + 255) / 256)

__global__ __launch_bounds__(256) void prep_kernel(
    const float* __restrict__ W_reduc, const float* __restrict__ b_reduc,
    const float* __restrict__ W_ap, const float* __restrict__ b_ap,
    const float* __restrict__ W_op, const float* __restrict__ b_op,
    const float* __restrict__ W_bi,
    unsigned short* __restrict__ WtR, unsigned short* __restrict__ WtAO,
    unsigned short* __restrict__ WtBi,
    float* __restrict__ bR, float* __restrict__ bAO, float* __restrict__ bBi)
{
    int idx = blockIdx.x * 256 + threadIdx.x;
    if (idx < SZ0) {
        int n = idx / D_, k = idx - n * D_;
        float v = (n < RED_) ? W_reduc[(size_t)k * RED_ + n] : 0.f;
        WtR[idx] = f2bf(v);
    } else if (idx < SZ0 + SZ1) {
        int i = idx - SZ0;
        int n = i >> 9, k = i & 511;
        float v = 0.f;
        if (k < RED_) {
            if (n < HID_)                      v = W_ap[(size_t)k * HID_ + n];
            else if (n >= 128 && n < 128+HID_) v = W_op[(size_t)k * HID_ + (n-128)];
        }
        WtAO[i] = f2bf(v);
    } else if (idx < SZ0 + SZ1 + SZ2) {
        int i = idx - SZ0 - SZ1;
        int n = i >> 7, k = i & 127;
        int p = n >> 7, h = n & 127;
        float v = (h < HID_ && k < HID_) ? W_bi[(size_t)k * RED_ + p * HID_ + h] : 0.f;
        WtBi[i] = f2bf(v);
        if (k == 0) bBi[n] = (h < HID_) ? W_bi[(size_t)HID_ * RED_ + p * HID_ + h] : 0.f;
    } else if (idx < SZ0 + SZ1 + SZ2 + SZ3) {
        int n = idx - SZ0 - SZ1 - SZ2;
        bR[n] = (n < RED_) ? b_reduc[n] : 0.f;
    } else if (idx < PREP_TOT) {
        int n = idx - SZ0 - SZ1 - SZ2 - SZ3;
        bAO[n] = (n < 128) ? ((n < HID_) ? b_ap[n] : 0.f)
                           : (((n-128) < HID_) ? b_op[n-128] : 0.f);
    }
}

// ---------------------------------------------------------------------------
// 1) GEMM1 + fused segment-mean, v4 (occupancy-first):
//    h = relu( segmean(bert)[16384,768] @ WtR[512,768]^T + bR ) -> bf16
// Tile 64 rows x 128 cols; grid (256, 4) = 1024 blocks = 4 blocks/CU.
// Waves 2x2, each 32 rows x 64 cols (acc[2][4], 8 MFMA/iter).
// A staged in-register: 1 span-row per thread (4 f32x4 loads -> 1
// ds_write_b128). B via global_load_lds. Double-buffered, 24 KB LDS.
// ---------------------------------------------------------------------------
__global__ __launch_bounds__(256) void gemm1_seg_kernel(
    const float* __restrict__ bert, const int* __restrict__ pos,
    const short* __restrict__ Bt, const float* __restrict__ bias,
    unsigned short* __restrict__ Co)
{
    // per buf: A 64x32 (2048 shorts) | B 128x32 (4096 shorts)
    __shared__ __align__(16) short lds[2][6144];

    const int t  = threadIdx.x;
    const int wv = t >> 6;
    const int ln = t & 63;
    const int wm = wv >> 1;        // 0..1: row half (32 rows)
    const int wn = wv & 1;         // 0..1: col half (64 cols)
    const int bm = blockIdx.x * 64;
    const int bn = blockIdx.y * 128;
    const int batch = bm >> 8;     // 64 rows never cross a 256-row batch

    const int srow = t >> 2;       // 0..63
    const int skc  = (t & 3) * 8;  // k offset (elements)

    // span row bases for my A row
    const int r = bm + srow;
    const int s = pos[r * 2 + 0];
    const int e = pos[r * 2 + 1];  // e == s when len == 1 -> (a+a)*0.5 == a
    const size_t rb0 = ((size_t)batch * S_ + s) * D_;
    const size_t rb1 = ((size_t)batch * S_ + e) * D_;

    f32x4 acc[2][4] = {};
    const int NT = D_ >> 5;   // 24

    // ---- prologue: stage kt=0 into buf 0 ----
    {
        #pragma unroll
        for (int q = 0; q < 2; ++q) {
            const short* g = Bt + (size_t)(bn + q * 64 + srow) * D_ + skc;
            GLOAD_LDS16(g, &lds[0][2048 + q * 2048 + wv * 512]);
        }
        f32x4 x0 = *(const f32x4*)(bert + rb0 + skc);
        f32x4 x1 = *(const f32x4*)(bert + rb0 + skc + 4);
        f32x4 y0 = *(const f32x4*)(bert + rb1 + skc);
        f32x4 y1 = *(const f32x4*)(bert + rb1 + skc + 4);
        f32x4 s0 = (x0 + y0) * 0.5f;
        f32x4 s1 = (x1 + y1) * 0.5f;
        union { short8 v; unsigned short u[8]; } o;
        #pragma unroll
        for (int j = 0; j < 4; ++j) { o.u[j] = f2bf(s0[j]); o.u[4+j] = f2bf(s1[j]); }
        *(short8*)(&lds[0][srow * 32 + skc]) = o.v;
    }
    __syncthreads();

    int cur = 0;
    const int lr = ln & 15;
    const int lk = (ln >> 4) * 8;

    for (int kt = 0; kt < NT; ++kt) {
        const bool more = (kt + 1 < NT);
        f32x4 x0, x1, y0, y1;
        if (more) {
            int col = (kt + 1) * 32 + skc;
            // issue A loads early (latency hides under MFMA below)
            x0 = *(const f32x4*)(bert + rb0 + col);
            x1 = *(const f32x4*)(bert + rb0 + col + 4);
            y0 = *(const f32x4*)(bert + rb1 + col);
            y1 = *(const f32x4*)(bert + rb1 + col + 4);
            // issue B gloads
            #pragma unroll
            for (int q = 0; q < 2; ++q) {
                const short* g = Bt + (size_t)(bn + q * 64 + srow) * D_ + (kt + 1) * 32 + skc;
                GLOAD_LDS16(g, &lds[cur ^ 1][2048 + q * 2048 + wv * 512]);
            }
        }

        const short* As = &lds[cur][0];
        const short* Bs = &lds[cur][2048];
        short8 a[2], b[4];
        #pragma unroll
        for (int fi = 0; fi < 2; ++fi)
            a[fi] = *(const short8*)(As + (wm * 32 + fi * 16 + lr) * 32 + lk);
        #pragma unroll
        for (int fj = 0; fj < 4; ++fj)
            b[fj] = *(const short8*)(Bs + (wn * 64 + fj * 16 + lr) * 32 + lk);
        #pragma unroll
        for (int fi = 0; fi < 2; ++fi)
            #pragma unroll
            for (int fj = 0; fj < 4; ++fj)
                acc[fi][fj] = __builtin_amdgcn_mfma_f32_16x16x32_bf16(
                    a[fi], b[fj], acc[fi][fj], 0, 0, 0);

        if (more) {
            f32x4 s0 = (x0 + y0) * 0.5f;
            f32x4 s1 = (x1 + y1) * 0.5f;
            union { short8 v; unsigned short u[8]; } o;
            #pragma unroll
            for (int j = 0; j < 4; ++j) { o.u[j] = f2bf(s0[j]); o.u[4+j] = f2bf(s1[j]); }
            *(short8*)(&lds[cur ^ 1][srow * 32 + skc]) = o.v;
        }

        __syncthreads();
        cur ^= 1;
    }

    const int row0 = bm + wm * 32 + (ln >> 4) * 4;
    const int col0 = bn + wn * 64 + lr;
    #pragma unroll
    for (int fi = 0; fi < 2; ++fi)
        #pragma unroll
        for (int rr = 0; rr < 4; ++rr) {
            int row = row0 + fi * 16 + rr;
            #pragma unroll
            for (int fj = 0; fj < 4; ++fj) {
                int col = col0 + fj * 16;
                float v = fmaxf(acc[fi][fj][rr] + bias[col], 0.f);
                Co[(size_t)row * REDP_ + col] = f2bf(v);
            }
        }
}

// ---------------------------------------------------------------------------
// 2) GEMM23 + tag heads (unchanged). grid (128, 2).
// ---------------------------------------------------------------------------
__global__ __launch_bounds__(256) void gemm23_tag_kernel(
    const short* __restrict__ A, const short* __restrict__ Bt,
    const float* __restrict__ bias,
    unsigned short* __restrict__ apOut, unsigned short* __restrict__ opOut,
    const float* __restrict__ Wap_tag, const float* __restrict__ bap_tag,
    const float* __restrict__ Wop_tag, const float* __restrict__ bop_tag,
    float* __restrict__ out_tag)
{
    __shared__ __align__(16) short lds[2][8192];
    __shared__ float tagf[128 * 101];
    __shared__ float Wtag[HID_ * TAGS_];
    __shared__ float Btag[TAGS_];

    const int t  = threadIdx.x;
    const int wv = t >> 6;
    const int ln = t & 63;
    const int wm = wv >> 1;
    const int wn = wv & 1;
    const int bm = blockIdx.x * 128;
    const int bn = blockIdx.y * 128;
    const int half = blockIdx.y;

    const float* Wt = half ? Wop_tag : Wap_tag;
    const float* bt = half ? bop_tag : bap_tag;
    for (int i = t; i < HID_ * TAGS_; i += 256) Wtag[i] = Wt[i];
    if (t < TAGS_) Btag[t] = bt[t];

    const int srow = t >> 2;
    const int skc  = (t & 3) * 8;
    const int NT = KEFF_ >> 5;   // 13

    f32x4 acc[4][4] = {};

    {
        #pragma unroll
        for (int q = 0; q < 2; ++q) {
            const short* g = A + (size_t)(bm + q * 64 + srow) * REDP_ + skc;
            GLOAD_LDS16(g, &lds[0][q * 2048 + wv * 512]);
        }
        #pragma unroll
        for (int q = 0; q < 2; ++q) {
            const short* g = Bt + (size_t)(bn + q * 64 + srow) * REDP_ + skc;
            GLOAD_LDS16(g, &lds[0][4096 + q * 2048 + wv * 512]);
        }
    }
    __syncthreads();

    int cur = 0;
    const int lr = ln & 15;
    const int lk = (ln >> 4) * 8;

    for (int kt = 0; kt < NT; ++kt) {
        if (kt + 1 < NT) {
            int k0 = (kt + 1) << 5;
            #pragma unroll
            for (int q = 0; q < 2; ++q) {
                const short* g = A + (size_t)(bm + q * 64 + srow) * REDP_ + k0 + skc;
                GLOAD_LDS16(g, &lds[cur ^ 1][q * 2048 + wv * 512]);
            }
            #pragma unroll
            for (int q = 0; q < 2; ++q) {
                const short* g = Bt + (size_t)(bn + q * 64 + srow) * REDP_ + k0 + skc;
                GLOAD_LDS16(g, &lds[cur ^ 1][4096 + q * 2048 + wv * 512]);
            }
        }

        const short* As = &lds[cur][0];
        const short* Bs = &lds[cur][4096];
        short8 a[4], b[4];
        #pragma unroll
        for (int fi = 0; fi < 4; ++fi)
            a[fi] = *(const short8*)(As + (wm * 64 + fi * 16 + lr) * 32 + lk);
        #pragma unroll
        for (int fj = 0; fj < 4; ++fj)
            b[fj] = *(const short8*)(Bs + (wn * 64 + fj * 16 + lr) * 32 + lk);
        #pragma unroll
        for (int fi = 0; fi < 4; ++fi)
            #pragma unroll
            for (int fj = 0; fj < 4; ++fj)
                acc[fi][fj] = __builtin_amdgcn_mfma_f32_16x16x32_bf16(
                    a[fi], b[fj], acc[fi][fj], 0, 0, 0);

        __syncthreads();
        cur ^= 1;
    }

    unsigned short* Co = half ? opOut : apOut;
    const int rl0 = wm * 64 + (ln >> 4) * 4;
    const int cl0 = wn * 64 + lr;
    #pragma unroll
    for (int fi = 0; fi < 4; ++fi)
        #pragma unroll
        for (int r = 0; r < 4; ++r) {
            int rl = rl0 + fi * 16 + r;
            #pragma unroll
            for (int fj = 0; fj < 4; ++fj) {
                int cl = cl0 + fj * 16;
                float v = fmaxf(acc[fi][fj][r] + bias[bn + cl], 0.f);
                Co[(size_t)(bm + rl) * 128 + cl] = f2bf(v);
                if (cl < 101) tagf[rl * 101 + cl] = v;
            }
        }
    __syncthreads();

    if (t < 128) {
        float s[TAGS_];
        #pragma unroll
        for (int g = 0; g < TAGS_; ++g) s[g] = Btag[g];
        const float* rowp = &tagf[t * 101];
        for (int k = 0; k < HID_; ++k) {
            float x = rowp[k];
            #pragma unroll
            for (int g = 0; g < TAGS_; ++g) s[g] += x * Wtag[k * TAGS_ + g];
        }
        float* o = out_tag + (size_t)half * (BL_ * TAGS_) + (size_t)(bm + t) * TAGS_;
        #pragma unroll
        for (int g = 0; g < TAGS_; ++g) o[g] = s[g];
    }
}

// ---------------------------------------------------------------------------
// 3) Fused biaffine + triplet (R13, unchanged): non-redundant aff build +
// swapped phase-C operands (lane's f32x4 = 4 consecutive ip -> dwordx4).
// grid (8 ip-tiles, 64 batches).
// ---------------------------------------------------------------------------
__global__ __launch_bounds__(256) void bi_triplet_kernel(
    const short* __restrict__ op, const short* __restrict__ ap,
    const short* __restrict__ WtBi, const float* __restrict__ bBi,
    float* __restrict__ out)
{
    __shared__ __align__(16) short As[16384];   // op j-tile, ks-subtiled
    __shared__ __align__(16) short Bs[16384];   // aff tile (built in phase A)
    __shared__ __align__(16) short Aap[4096];   // ap 32 rows, kf-subtiled

    const int t  = threadIdx.x;
    const int wv = t >> 6;
    const int ln = t & 63;
    const int wm = wv >> 1;
    const int wn = wv & 1;
    const int ipt = blockIdx.x;          // 0..7
    const int b   = blockIdx.y;          // 0..63

    const short* opB = op + (size_t)b * 256 * HIDP_;
    const short* apB = ap + ((size_t)b * 256 + ipt * 32) * HIDP_;

    const int rsub = ln >> 2;
    const int j8   = (ln & 3) * 8;

    // stage op j-tile 0 -> As, and ap 32 rows -> Aap
    #pragma unroll
    for (int i = 0; i < 8; ++i) {
        int ks = i >> 1, hf = i & 1;
        int rloc = wv * 32 + hf * 16;
        const short* gA = opB + (size_t)(rloc + rsub) * HIDP_ + ks * 32 + j8;
        GLOAD_LDS16(gA, &As[ks * 4096 + rloc * 32]);
    }
    #pragma unroll
    for (int q = 0; q < 2; ++q) {
        int kf   = q * 2 + (wv >> 1);
        int irow = (wv & 1) * 16 + (ln >> 2);
        const short* gA = apB + (size_t)irow * HIDP_ + kf * 32 + (ln & 3) * 8;
        GLOAD_LDS16(gA, &Aap[q * 2048 + wv * 512]);
    }
    __syncthreads();

    const int lr = ln & 15;
    const int lk = (ln >> 4) * 8;
    const int hbase = wv * 32;          // each wave owns 32 h-columns

    // A) aff sub-GEMM: M=32 (i), N=32/wave (h), K=128; 4 p-slices
    #pragma unroll
    for (int p = 0; p < 4; ++p) {
        f32x4 acc2[2][2] = {};
        const short* Wp = WtBi + (size_t)(p * 128) * HIDP_;
        #pragma unroll
        for (int kf = 0; kf < 4; ++kf) {
            short8 a2[2], b2[2];
            #pragma unroll
            for (int fm = 0; fm < 2; ++fm)
                a2[fm] = *(const short8*)(Aap + kf * 1024 + (fm * 16 + lr) * 32 + lk);
            #pragma unroll
            for (int fn = 0; fn < 2; ++fn)
                b2[fn] = *(const short8*)(Wp + (size_t)(hbase + fn * 16 + lr) * HIDP_ + kf * 32 + lk);
            #pragma unroll
            for (int fm = 0; fm < 2; ++fm)
                #pragma unroll
                for (int fn = 0; fn < 2; ++fn)
                    acc2[fm][fn] = __builtin_amdgcn_mfma_f32_16x16x32_bf16(
                        a2[fm], b2[fn], acc2[fm][fn], 0, 0, 0);
        }
        // deposit aff -> Bs (triplet B layout: row ip_local = i*4+p, k = h)
        #pragma unroll
        for (int fm = 0; fm < 2; ++fm)
            #pragma unroll
            for (int fn = 0; fn < 2; ++fn) {
                int h = hbase + fn * 16 + lr;
                float bias = bBi[p * 128 + h];
                #pragma unroll
                for (int r = 0; r < 4; ++r) {
                    int i = fm * 16 + (ln >> 4) * 4 + r;
                    float v = acc2[fm][fn][r] + bias;
                    Bs[(h >> 5) * 4096 + (i * 4 + p) * 32 + (h & 31)] = (short)f2bf(v);
                }
            }
    }
    __syncthreads();

    // C) triplet: two j-tiles vs Bs, swapped operands (aff = A, op = B).
    float* Ob = out + (size_t)b * 256 * 1024;
    #pragma unroll
    for (int jt = 0; jt < 2; ++jt) {
        f32x4 acc[4][4] = {};   // [fa: aff/ip frag][fo: op/j frag]
        #pragma unroll
        for (int ks = 0; ks < 4; ++ks) {
            short8 af[4], of[4];
            #pragma unroll
            for (int fa = 0; fa < 4; ++fa)
                af[fa] = *(const short8*)(Bs + ks * 4096 + (wn * 64 + fa * 16 + lr) * 32 + lk);
            #pragma unroll
            for (int fo = 0; fo < 4; ++fo)
                of[fo] = *(const short8*)(As + ks * 4096 + (wm * 64 + fo * 16 + lr) * 32 + lk);
            #pragma unroll
            for (int fa = 0; fa < 4; ++fa)
                #pragma unroll
                for (int fo = 0; fo < 4; ++fo)
                    acc[fa][fo] = __builtin_amdgcn_mfma_f32_16x16x32_bf16(
                        af[fa], of[fo], acc[fa][fo], 0, 0, 0);
        }

        if (jt == 0) {
            __syncthreads();   // all waves done reading As
            #pragma unroll
            for (int i = 0; i < 8; ++i) {
                int ks = i >> 1, hf = i & 1;
                int rloc = wv * 32 + hf * 16;
                const short* gA = opB + (size_t)(128 + rloc + rsub) * HIDP_ + ks * 32 + j8;
                GLOAD_LDS16(gA, &As[ks * 4096 + rloc * 32]);
            }
        }

        const int jb  = jt * 128 + wm * 64 + lr;
        const int ipb = ipt * 128 + wn * 64 + (ln >> 4) * 4;
        #pragma unroll
        for (int fa = 0; fa < 4; ++fa) {
            int ip0 = ipb + fa * 16;
            #pragma unroll
            for (int fo = 0; fo < 4; ++fo) {
                int j = jb + fo * 16;
                *(f32x4*)(Ob + (size_t)j * 1024 + ip0) = acc[fa][fo];
            }
        }

        if (jt == 0) __syncthreads();   // As(j=1) ready
    }
}

// ---------------------------------------------------------------------------
extern "C" void kernel_launch(void* const* d_in, const int* in_sizes, int n_in,
                              void* d_out, int out_size, void* d_ws, size_t ws_size,
                              hipStream_t stream)
{
    const float* bert     = (const float*)d_in[0];
    const int*   pos      = (const int*)  d_in[1];
    const float* W_reduc  = (const float*)d_in[2];
    const float* b_reduc  = (const float*)d_in[3];
    const float* W_ap     = (const float*)d_in[4];
    const float* b_ap     = (const float*)d_in[5];
    const float* W_op     = (const float*)d_in[6];
    const float* b_op     = (const float*)d_in[7];
    const float* W_ap_tag = (const float*)d_in[8];
    const float* b_ap_tag = (const float*)d_in[9];
    const float* W_op_tag = (const float*)d_in[10];
    const float* b_op_tag = (const float*)d_in[11];
    const float* W_bi     = (const float*)d_in[12];

    float* out = (float*)d_out;

    // Workspace layout (bytes; all 16B-aligned)
    char* ws = (char*)d_ws;
    unsigned short* h      = (unsigned short*)ws; ws += (size_t)BL_ * REDP_ * 2;
    unsigned short* ap     = (unsigned short*)ws; ws += (size_t)BL_ * HIDP_ * 2;
    unsigned short* opv    = (unsigned short*)ws; ws += (size_t)BL_ * HIDP_ * 2;
    unsigned short* WtR    = (unsigned short*)ws; ws += (size_t)REDP_ * D_ * 2;
    unsigned short* WtAO   = (unsigned short*)ws; ws += (size_t)NAO_ * REDP_ * 2;
    unsigned short* WtBi   = (unsigned short*)ws; ws += (size_t)NBI_ * HIDP_ * 2;
    float* bR  = (float*)ws;  ws += REDP_ * 4;
    float* bAO = (float*)ws;  ws += NAO_ * 4;
    float* bBi = (float*)ws;  ws += NBI_ * 4;

    // 0) weight/bias prep
    prep_kernel<<<PREP_BLOCKS, 256, 0, stream>>>(
        W_reduc, b_reduc, W_ap, b_ap, W_op, b_op, W_bi,
        WtR, WtAO, WtBi, bR, bAO, bBi);

    // 1) h = relu(segmean(bert) @ W_reduc + b), fused, 64x128 tiles (4/CU)
    gemm1_seg_kernel<<<dim3(BL_ / 64, REDP_ / 128), 256, 0, stream>>>(
        bert, pos, (const short*)WtR, bR, h);

    // 2) ap|op = relu(h @ [W_ap|W_op] + b) + tag heads (K=416, 13 tiles)
    gemm23_tag_kernel<<<dim3(BL_ / 128, 2), 256, 0, stream>>>(
        (const short*)h, (const short*)WtAO, bAO, ap, opv,
        W_ap_tag, b_ap_tag, W_op_tag, b_op_tag, out);

    // 3) fused biaffine + triplet -> out[163840 : ]
    bi_triplet_kernel<<<dim3(8, B_), 256, 0, stream>>>(
        (const short*)opv, (const short*)ap, (const short*)WtBi, bBi,
        out + 2 * BL_ * TAGS_);
}

// Round 15
// 76.682 us; speedup vs baseline: 1.1400x; 1.1400x over previous
//
#include <hip/hip_runtime.h>
#include <hip/hip_bf16.h>

// Problem constants
#define B_    64
#define S_    512
#define L_    256
#define D_    768      // K of GEMM1
#define RED_  400
#define REDP_ 512      // padded N of GEMM1 / K-stride of GEMM23
#define KEFF_ 416      // effective K of GEMM23 (13 k-tiles; h cols 400.. are 0)
#define HID_  100
#define HIDP_ 128      // padded N of GEMM23 / K of aff+triplet
#define TAGS_ 5
#define POL_  4
#define NBI_  512      // aff padded N (4 * 128)
#define NAO_  256      // fused ap|op GEMM N
#define BL_   (B_ * L_)  // 16384

typedef __attribute__((ext_vector_type(8))) short short8;
typedef __attribute__((ext_vector_type(4))) float f32x4;
typedef __attribute__((ext_vector_type(4))) unsigned short u16x4;

#define GLOAD_LDS16(gp, lp) __builtin_amdgcn_global_load_lds( \
    (const __attribute__((address_space(1))) void*)(gp),      \
    (__attribute__((address_space(3))) void*)(lp), 16, 0, 0)

__device__ inline float bf2f(unsigned short u) {
    union { unsigned int i; float f; } c; c.i = ((unsigned)u) << 16; return c.f;
}
__device__ inline unsigned short f2bf(float f) {
    __hip_bfloat16 h = __float2bfloat16(f);
    unsigned short u;
    __builtin_memcpy(&u, &h, 2);
    return u;
}

// ---------------------------------------------------------------------------
// 0) PREP: weight/bias prep only.
// ---------------------------------------------------------------------------
#define SZ0 393216
#define SZ1 131072
#define SZ2 65536
#define SZ3 512
#define SZ4 256
#define PREP_TOT (SZ0 + SZ1 + SZ2 + SZ3 + SZ4)
#define PREP_BLOCKS ((PREP_TOT + 255) / 256)

__global__ __launch_bounds__(256) void prep_kernel(
    const float* __restrict__ W_reduc, const float* __restrict__ b_reduc,
    const float* __restrict__ W_ap, const float* __restrict__ b_ap,
    const float* __restrict__ W_op, const float* __restrict__ b_op,
    const float* __restrict__ W_bi,
    unsigned short* __restrict__ WtR, unsigned short* __restrict__ WtAO,
    unsigned short* __restrict__ WtBi,
    float* __restrict__ bR, float* __restrict__ bAO, float* __restrict__ bBi)
{
    int idx = blockIdx.x * 256 + threadIdx.x;
    if (idx < SZ0) {
        int n = idx / D_, k = idx - n * D_;
        float v = (n < RED_) ? W_reduc[(size_t)k * RED_ + n] : 0.f;
        WtR[idx] = f2bf(v);
    } else if (idx < SZ0 + SZ1) {
        int i = idx - SZ0;
        int n = i >> 9, k = i & 511;
        float v = 0.f;
        if (k < RED_) {
            if (n < HID_)                      v = W_ap[(size_t)k * HID_ + n];
            else if (n >= 128 && n < 128+HID_) v = W_op[(size_t)k * HID_ + (n-128)];
        }
        WtAO[i] = f2bf(v);
    } else if (idx < SZ0 + SZ1 + SZ2) {
        int i = idx - SZ0 - SZ1;
        int n = i >> 7, k = i & 127;
        int p = n >> 7, h = n & 127;
        float v = (h < HID_ && k < HID_) ? W_bi[(size_t)k * RED_ + p * HID_ + h] : 0.f;
        WtBi[i] = f2bf(v);
        if (k == 0) bBi[n] = (h < HID_) ? W_bi[(size_t)HID_ * RED_ + p * HID_ + h] : 0.f;
    } else if (idx < SZ0 + SZ1 + SZ2 + SZ3) {
        int n = idx - SZ0 - SZ1 - SZ2;
        bR[n] = (n < RED_) ? b_reduc[n] : 0.f;
    } else if (idx < PREP_TOT) {
        int n = idx - SZ0 - SZ1 - SZ2 - SZ3;
        bAO[n] = (n < 128) ? ((n < HID_) ? b_ap[n] : 0.f)
                           : (((n-128) < HID_) ? b_op[n-128] : 0.f);
    }
}

// ---------------------------------------------------------------------------
// 1) GEMM1 + fused segment-mean (best measured config):
//    h = relu( segmean(bert)[16384,768] @ WtR[512,768]^T + bR ) -> bf16
// Tile 64 rows x 256 cols; grid (256, 2) = 512 blocks (2 blocks/CU).
// Each wave: 64 rows x 64 cols, acc[4][4]. A staged in-register (span avg,
// 1 ds_write_b128/thread/ktile); B via global_load_lds. Double-buffered.
// ---------------------------------------------------------------------------
__global__ __launch_bounds__(256) void gemm1_seg_kernel(
    const float* __restrict__ bert, const int* __restrict__ pos,
    const short* __restrict__ Bt, const float* __restrict__ bias,
    unsigned short* __restrict__ Co)
{
    // per buf: A 64x32 (2048 shorts) | B 256x32 (8192 shorts)
    __shared__ __align__(16) short lds[2][10240];

    const int t  = threadIdx.x;
    const int wv = t >> 6;
    const int ln = t & 63;
    const int bm  = blockIdx.x * 64;
    const int bnh = blockIdx.y * 256;
    const int batch = bm >> 8;     // 64 rows never cross a batch (256-row) boundary

    const int srow = t >> 2;       // 0..63
    const int skc  = (t & 3) * 8;  // k offset (elements)

    // span row bases for my A row
    const int r = bm + srow;
    const int s = pos[r * 2 + 0];
    const int e = pos[r * 2 + 1];  // e == s when len == 1 -> (a+a)*0.5 == a
    const size_t rb0 = ((size_t)batch * S_ + s) * D_;
    const size_t rb1 = ((size_t)batch * S_ + e) * D_;

    f32x4 acc[4][4] = {};
    const int NT = D_ >> 5;   // 24

    // ---- prologue: stage kt=0 into buf 0 ----
    {
        #pragma unroll
        for (int q = 0; q < 4; ++q) {
            const short* g = Bt + (size_t)(bnh + q * 64 + srow) * D_ + skc;
            GLOAD_LDS16(g, &lds[0][2048 + q * 2048 + wv * 512]);
        }
        f32x4 x0 = *(const f32x4*)(bert + rb0 + skc);
        f32x4 x1 = *(const f32x4*)(bert + rb0 + skc + 4);
        f32x4 y0 = *(const f32x4*)(bert + rb1 + skc);
        f32x4 y1 = *(const f32x4*)(bert + rb1 + skc + 4);
        f32x4 s0 = (x0 + y0) * 0.5f;
        f32x4 s1 = (x1 + y1) * 0.5f;
        union { short8 v; unsigned short u[8]; } o;
        #pragma unroll
        for (int j = 0; j < 4; ++j) { o.u[j] = f2bf(s0[j]); o.u[4+j] = f2bf(s1[j]); }
        *(short8*)(&lds[0][srow * 32 + skc]) = o.v;
    }
    __syncthreads();

    int cur = 0;
    const int lr = ln & 15;
    const int lk = (ln >> 4) * 8;

    for (int kt = 0; kt < NT; ++kt) {
        const bool more = (kt + 1 < NT);
        f32x4 x0, x1, y0, y1;
        if (more) {
            int col = (kt + 1) * 32 + skc;
            // issue A loads early (latency hides under MFMA below)
            x0 = *(const f32x4*)(bert + rb0 + col);
            x1 = *(const f32x4*)(bert + rb0 + col + 4);
            y0 = *(const f32x4*)(bert + rb1 + col);
            y1 = *(const f32x4*)(bert + rb1 + col + 4);
            // issue B gloads
            #pragma unroll
            for (int q = 0; q < 4; ++q) {
                const short* g = Bt + (size_t)(bnh + q * 64 + srow) * D_ + (kt + 1) * 32 + skc;
                GLOAD_LDS16(g, &lds[cur ^ 1][2048 + q * 2048 + wv * 512]);
            }
        }

        const short* As = &lds[cur][0];
        const short* Bs = &lds[cur][2048];
        short8 a[4], b[4];
        #pragma unroll
        for (int fi = 0; fi < 4; ++fi)
            a[fi] = *(const short8*)(As + (fi * 16 + lr) * 32 + lk);
        #pragma unroll
        for (int fj = 0; fj < 4; ++fj)
            b[fj] = *(const short8*)(Bs + (wv * 64 + fj * 16 + lr) * 32 + lk);
        #pragma unroll
        for (int fi = 0; fi < 4; ++fi)
            #pragma unroll
            for (int fj = 0; fj < 4; ++fj)
                acc[fi][fj] = __builtin_amdgcn_mfma_f32_16x16x32_bf16(
                    a[fi], b[fj], acc[fi][fj], 0, 0, 0);

        if (more) {
            f32x4 s0 = (x0 + y0) * 0.5f;
            f32x4 s1 = (x1 + y1) * 0.5f;
            union { short8 v; unsigned short u[8]; } o;
            #pragma unroll
            for (int j = 0; j < 4; ++j) { o.u[j] = f2bf(s0[j]); o.u[4+j] = f2bf(s1[j]); }
            *(short8*)(&lds[cur ^ 1][srow * 32 + skc]) = o.v;
        }

        __syncthreads();
        cur ^= 1;
    }

    const int row0 = bm + (ln >> 4) * 4;
    const int col0 = bnh + wv * 64 + lr;
    #pragma unroll
    for (int fi = 0; fi < 4; ++fi)
        #pragma unroll
        for (int rr = 0; rr < 4; ++rr) {
            int row = row0 + fi * 16 + rr;
            #pragma unroll
            for (int fj = 0; fj < 4; ++fj) {
                int col = col0 + fj * 16;
                float v = fmaxf(acc[fi][fj][rr] + bias[col], 0.f);
                Co[(size_t)row * REDP_ + col] = f2bf(v);
            }
        }
}

// ---------------------------------------------------------------------------
// 2) GEMM23 + tag heads. grid (128, 2).
// ---------------------------------------------------------------------------
__global__ __launch_bounds__(256) void gemm23_tag_kernel(
    const short* __restrict__ A, const short* __restrict__ Bt,
    const float* __restrict__ bias,
    unsigned short* __restrict__ apOut, unsigned short* __restrict__ opOut,
    const float* __restrict__ Wap_tag, const float* __restrict__ bap_tag,
    const float* __restrict__ Wop_tag, const float* __restrict__ bop_tag,
    float* __restrict__ out_tag)
{
    __shared__ __align__(16) short lds[2][8192];
    __shared__ float tagf[128 * 101];
    __shared__ float Wtag[HID_ * TAGS_];
    __shared__ float Btag[TAGS_];

    const int t  = threadIdx.x;
    const int wv = t >> 6;
    const int ln = t & 63;
    const int wm = wv >> 1;
    const int wn = wv & 1;
    const int bm = blockIdx.x * 128;
    const int bn = blockIdx.y * 128;
    const int half = blockIdx.y;

    const float* Wt = half ? Wop_tag : Wap_tag;
    const float* bt = half ? bop_tag : bap_tag;
    for (int i = t; i < HID_ * TAGS_; i += 256) Wtag[i] = Wt[i];
    if (t < TAGS_) Btag[t] = bt[t];

    const int srow = t >> 2;
    const int skc  = (t & 3) * 8;
    const int NT = KEFF_ >> 5;   // 13

    f32x4 acc[4][4] = {};

    {
        #pragma unroll
        for (int q = 0; q < 2; ++q) {
            const short* g = A + (size_t)(bm + q * 64 + srow) * REDP_ + skc;
            GLOAD_LDS16(g, &lds[0][q * 2048 + wv * 512]);
        }
        #pragma unroll
        for (int q = 0; q < 2; ++q) {
            const short* g = Bt + (size_t)(bn + q * 64 + srow) * REDP_ + skc;
            GLOAD_LDS16(g, &lds[0][4096 + q * 2048 + wv * 512]);
        }
    }
    __syncthreads();

    int cur = 0;
    const int lr = ln & 15;
    const int lk = (ln >> 4) * 8;

    for (int kt = 0; kt < NT; ++kt) {
        if (kt + 1 < NT) {
            int k0 = (kt + 1) << 5;
            #pragma unroll
            for (int q = 0; q < 2; ++q) {
                const short* g = A + (size_t)(bm + q * 64 + srow) * REDP_ + k0 + skc;
                GLOAD_LDS16(g, &lds[cur ^ 1][q * 2048 + wv * 512]);
            }
            #pragma unroll
            for (int q = 0; q < 2; ++q) {
                const short* g = Bt + (size_t)(bn + q * 64 + srow) * REDP_ + k0 + skc;
                GLOAD_LDS16(g, &lds[cur ^ 1][4096 + q * 2048 + wv * 512]);
            }
        }

        const short* As = &lds[cur][0];
        const short* Bs = &lds[cur][4096];
        short8 a[4], b[4];
        #pragma unroll
        for (int fi = 0; fi < 4; ++fi)
            a[fi] = *(const short8*)(As + (wm * 64 + fi * 16 + lr) * 32 + lk);
        #pragma unroll
        for (int fj = 0; fj < 4; ++fj)
            b[fj] = *(const short8*)(Bs + (wn * 64 + fj * 16 + lr) * 32 + lk);
        #pragma unroll
        for (int fi = 0; fi < 4; ++fi)
            #pragma unroll
            for (int fj = 0; fj < 4; ++fj)
                acc[fi][fj] = __builtin_amdgcn_mfma_f32_16x16x32_bf16(
                    a[fi], b[fj], acc[fi][fj], 0, 0, 0);

        __syncthreads();
        cur ^= 1;
    }

    unsigned short* Co = half ? opOut : apOut;
    const int rl0 = wm * 64 + (ln >> 4) * 4;
    const int cl0 = wn * 64 + lr;
    #pragma unroll
    for (int fi = 0; fi < 4; ++fi)
        #pragma unroll
        for (int r = 0; r < 4; ++r) {
            int rl = rl0 + fi * 16 + r;
            #pragma unroll
            for (int fj = 0; fj < 4; ++fj) {
                int cl = cl0 + fj * 16;
                float v = fmaxf(acc[fi][fj][r] + bias[bn + cl], 0.f);
                Co[(size_t)(bm + rl) * 128 + cl] = f2bf(v);
                if (cl < 101) tagf[rl * 101 + cl] = v;
            }
        }
    __syncthreads();

    if (t < 128) {
        float s[TAGS_];
        #pragma unroll
        for (int g = 0; g < TAGS_; ++g) s[g] = Btag[g];
        const float* rowp = &tagf[t * 101];
        for (int k = 0; k < HID_; ++k) {
            float x = rowp[k];
            #pragma unroll
            for (int g = 0; g < TAGS_; ++g) s[g] += x * Wtag[k * TAGS_ + g];
        }
        float* o = out_tag + (size_t)half * (BL_ * TAGS_) + (size_t)(bm + t) * TAGS_;
        #pragma unroll
        for (int g = 0; g < TAGS_; ++g) o[g] = s[g];
    }
}

// ---------------------------------------------------------------------------
// 3) Fused biaffine + triplet, NON-redundant. grid (8 ip-tiles, 64 batches).
// Per block (b, ipt):
//   A) aff[128 ip][128 h] computed ONCE (M=32 GEMM: Aap(LDS) x WtBi(L2))
//      -> deposit bf16 into Bs (triplet B layout).
//   C) loop jt=0,1: triplet 128x128 vs Bs; op j-tile restaged between.
// LDS 72 KB -> 2 blocks/CU.
// ---------------------------------------------------------------------------
__global__ __launch_bounds__(256) void bi_triplet_kernel(
    const short* __restrict__ op, const short* __restrict__ ap,
    const short* __restrict__ WtBi, const float* __restrict__ bBi,
    float* __restrict__ out)
{
    __shared__ __align__(16) short As[16384];   // op j-tile, ks-subtiled
    __shared__ __align__(16) short Bs[16384];   // aff tile (built in phase A)
    __shared__ __align__(16) short Aap[4096];   // ap 32 rows, kf-subtiled

    const int t  = threadIdx.x;
    const int wv = t >> 6;
    const int ln = t & 63;
    const int wm = wv >> 1;
    const int wn = wv & 1;
    const int ipt = blockIdx.x;          // 0..7
    const int b   = blockIdx.y;          // 0..63

    const short* opB = op + (size_t)b * 256 * HIDP_;
    const short* apB = ap + ((size_t)b * 256 + ipt * 32) * HIDP_;

    const int rsub = ln >> 2;
    const int j8   = (ln & 3) * 8;

    // stage op j-tile 0 -> As, and ap 32 rows -> Aap
    #pragma unroll
    for (int i = 0; i < 8; ++i) {
        int ks = i >> 1, hf = i & 1;
        int rloc = wv * 32 + hf * 16;
        const short* gA = opB + (size_t)(rloc + rsub) * HIDP_ + ks * 32 + j8;
        GLOAD_LDS16(gA, &As[ks * 4096 + rloc * 32]);
    }
    #pragma unroll
    for (int q = 0; q < 2; ++q) {
        int kf   = q * 2 + (wv >> 1);
        int irow = (wv & 1) * 16 + (ln >> 2);
        const short* gA = apB + (size_t)irow * HIDP_ + kf * 32 + (ln & 3) * 8;
        GLOAD_LDS16(gA, &Aap[q * 2048 + wv * 512]);
    }
    __syncthreads();

    const int lr = ln & 15;
    const int lk = (ln >> 4) * 8;
    const int hbase = wv * 32;          // each wave owns 32 h-columns

    // A) aff sub-GEMM: M=32 (i), N=32/wave (h), K=128; 4 p-slices
    #pragma unroll
    for (int p = 0; p < 4; ++p) {
        f32x4 acc2[2][2] = {};
        const short* Wp = WtBi + (size_t)(p * 128) * HIDP_;
        #pragma unroll
        for (int kf = 0; kf < 4; ++kf) {
            short8 a2[2], b2[2];
            #pragma unroll
            for (int fm = 0; fm < 2; ++fm)
                a2[fm] = *(const short8*)(Aap + kf * 1024 + (fm * 16 + lr) * 32 + lk);
            #pragma unroll
            for (int fn = 0; fn < 2; ++fn)
                b2[fn] = *(const short8*)(Wp + (size_t)(hbase + fn * 16 + lr) * HIDP_ + kf * 32 + lk);
            #pragma unroll
            for (int fm = 0; fm < 2; ++fm)
                #pragma unroll
                for (int fn = 0; fn < 2; ++fn)
                    acc2[fm][fn] = __builtin_amdgcn_mfma_f32_16x16x32_bf16(
                        a2[fm], b2[fn], acc2[fm][fn], 0, 0, 0);
        }
        // deposit aff -> Bs (triplet B layout: row ip_local = i*4+p, k = h)
        #pragma unroll
        for (int fm = 0; fm < 2; ++fm)
            #pragma unroll
            for (int fn = 0; fn < 2; ++fn) {
                int h = hbase + fn * 16 + lr;
                float bias = bBi[p * 128 + h];
                #pragma unroll
                for (int r = 0; r < 4; ++r) {
                    int i = fm * 16 + (ln >> 4) * 4 + r;
                    float v = acc2[fm][fn][r] + bias;
                    Bs[(h >> 5) * 4096 + (i * 4 + p) * 32 + (h & 31)] = (short)f2bf(v);
                }
            }
    }
    __syncthreads();

    // C) triplet: two j-tiles vs Bs
    float* Ob = out + (size_t)b * 256 * 1024;
    #pragma unroll
    for (int jt = 0; jt < 2; ++jt) {
        f32x4 acc[4][4] = {};
        #pragma unroll
        for (int ks = 0; ks < 4; ++ks) {
            short8 a[4], bf[4];
            #pragma unroll
            for (int fi = 0; fi < 4; ++fi)
                a[fi] = *(const short8*)(As + ks * 4096 + (wm * 64 + fi * 16 + lr) * 32 + lk);
            #pragma unroll
            for (int fj = 0; fj < 4; ++fj)
                bf[fj] = *(const short8*)(Bs + ks * 4096 + (wn * 64 + fj * 16 + lr) * 32 + lk);
            #pragma unroll
            for (int fi = 0; fi < 4; ++fi)
                #pragma unroll
                for (int fj = 0; fj < 4; ++fj)
                    acc[fi][fj] = __builtin_amdgcn_mfma_f32_16x16x32_bf16(
                        a[fi], bf[fj], acc[fi][fj], 0, 0, 0);
        }

        if (jt == 0) {
            __syncthreads();   // all waves done reading As
            // restage op j-tile 1 while storing jt=0 results
            #pragma unroll
            for (int i = 0; i < 8; ++i) {
                int ks = i >> 1, hf = i & 1;
                int rloc = wv * 32 + hf * 16;
                const short* gA = opB + (size_t)(128 + rloc + rsub) * HIDP_ + ks * 32 + j8;
                GLOAD_LDS16(gA, &As[ks * 4096 + rloc * 32]);
            }
        }

        const int row0 = jt * 128 + wm * 64 + (ln >> 4) * 4;
        const int col0 = ipt * 128 + wn * 64 + lr;
        #pragma unroll
        for (int fi = 0; fi < 4; ++fi)
            #pragma unroll
            for (int r = 0; r < 4; ++r) {
                int row = row0 + fi * 16 + r;
                #pragma unroll
                for (int fj = 0; fj < 4; ++fj)
                    Ob[(size_t)row * 1024 + col0 + fj * 16] = acc[fi][fj][r];
            }

        if (jt == 0) __syncthreads();   // As(j=1) ready
    }
}

// ---------------------------------------------------------------------------
extern "C" void kernel_launch(void* const* d_in, const int* in_sizes, int n_in,
                              void* d_out, int out_size, void* d_ws, size_t ws_size,
                              hipStream_t stream)
{
    const float* bert     = (const float*)d_in[0];
    const int*   pos      = (const int*)  d_in[1];
    const float* W_reduc  = (const float*)d_in[2];
    const float* b_reduc  = (const float*)d_in[3];
    const float* W_ap     = (const float*)d_in[4];
    const float* b_ap     = (const float*)d_in[5];
    const float* W_op     = (const float*)d_in[6];
    const float* b_op     = (const float*)d_in[7];
    const float* W_ap_tag = (const float*)d_in[8];
    const float* b_ap_tag = (const float*)d_in[9];
    const float* W_op_tag = (const float*)d_in[10];
    const float* b_op_tag = (const float*)d_in[11];
    const float* W_bi     = (const float*)d_in[12];

    float* out = (float*)d_out;

    // Workspace layout (bytes; all 16B-aligned)
    char* ws = (char*)d_ws;
    unsigned short* h      = (unsigned short*)ws; ws += (size_t)BL_ * REDP_ * 2;
    unsigned short* ap     = (unsigned short*)ws; ws += (size_t)BL_ * HIDP_ * 2;
    unsigned short* opv    = (unsigned short*)ws; ws += (size_t)BL_ * HIDP_ * 2;
    unsigned short* WtR    = (unsigned short*)ws; ws += (size_t)REDP_ * D_ * 2;
    unsigned short* WtAO   = (unsigned short*)ws; ws += (size_t)NAO_ * REDP_ * 2;
    unsigned short* WtBi   = (unsigned short*)ws; ws += (size_t)NBI_ * HIDP_ * 2;
    float* bR  = (float*)ws;  ws += REDP_ * 4;
    float* bAO = (float*)ws;  ws += NAO_ * 4;
    float* bBi = (float*)ws;  ws += NBI_ * 4;

    // 0) weight/bias prep
    prep_kernel<<<PREP_BLOCKS, 256, 0, stream>>>(
        W_reduc, b_reduc, W_ap, b_ap, W_op, b_op, W_bi,
        WtR, WtAO, WtBi, bR, bAO, bBi);

    // 1) h = relu(segmean(bert) @ W_reduc + b), seg-mean fused, 512 blocks
    gemm1_seg_kernel<<<dim3(BL_ / 64, 2), 256, 0, stream>>>(
        bert, pos, (const short*)WtR, bR, h);

    // 2) ap|op = relu(h @ [W_ap|W_op] + b) + tag heads (K=416, 13 tiles)
    gemm23_tag_kernel<<<dim3(BL_ / 128, 2), 256, 0, stream>>>(
        (const short*)h, (const short*)WtAO, bAO, ap, opv,
        W_ap_tag, b_ap_tag, W_op_tag, b_op_tag, out);

    // 3) fused biaffine + triplet -> out[163840 : ]
    bi_triplet_kernel<<<dim3(8, B_), 256, 0, stream>>>(
        (const short*)opv, (const short*)ap, (const short*)WtBi, bBi,
        out + 2 * BL_ * TAGS_);
}